// Round 6
// baseline (872.557 us; speedup 1.0000x reference)
//
#include <hip/hip_runtime.h>

// VQ-VAE forward, MI355X round 6: R5 + vq_k rewritten for 4 points/thread
// (LDS-issue amortization). fp32 I/O, bf16 intermediates.

typedef __attribute__((ext_vector_type(8))) short     short8;
typedef __attribute__((ext_vector_type(8))) __bf16    bf16x8;
typedef __attribute__((ext_vector_type(4))) float     f32x4;

#define BATCH 32

__device__ __forceinline__ float b2f(unsigned short b) {
  union { unsigned u; float f; } v; v.u = ((unsigned)b) << 16; return v.f;
}
__device__ __forceinline__ unsigned short f2b(float f) {  // round-to-nearest-even
  union { float f; unsigned u; } v; v.f = f;
  unsigned r = v.u + 0x7FFF + ((v.u >> 16) & 1);
  return (unsigned short)(r >> 16);
}

// ---------------- weight prep: reorganize to [tap][co][ci] bf16 -------------
__global__ __launch_bounds__(256) void prep2_k(const float* __restrict__ w,
                                               unsigned short* __restrict__ wq) {
  const int i = blockIdx.x*256 + threadIdx.x;                 // 131072 exact
  const int ci = i & 63, co = (i >> 6) & 127, t = i >> 13;
  wq[i] = f2b(w[(co*64 + ci)*16 + t]);                        // ew2 OIHW(128,64,4,4)
}
__global__ __launch_bounds__(256) void prep3_k(const float* __restrict__ w,
                                               unsigned short* __restrict__ wq) {
  const int i = blockIdx.x*256 + threadIdx.x;                 // 36864 exact
  const int ci = i & 127, co = (i >> 7) & 31, t = i >> 12;
  wq[i] = f2b(w[(co*128 + ci)*9 + t]);                        // ew3 OIHW(32,128,3,3)
}
__global__ __launch_bounds__(256) void prep4_k(const float* __restrict__ w,
                                               unsigned short* __restrict__ wq) {
  const int i = blockIdx.x*256 + threadIdx.x;                 // 36864 exact
  const int ci = i & 31, co = (i >> 5) & 127, t = i >> 12;
  wq[i] = f2b(w[(ci*128 + co)*9 + (8 - t)]);                  // dw1(32,128,3,3), flipped
}
__global__ __launch_bounds__(256) void prep5_k(const float* __restrict__ w,
                                               unsigned short* __restrict__ wq) {
  const int i = blockIdx.x*256 + threadIdx.x;                 // 131072 exact
  const int ci = i & 127, co = (i >> 7) & 63, t = (i >> 13) & 3, p = i >> 15;
  const int ky = 2 - 2*(t >> 1) + (1 - (p >> 1));
  const int kx = 2 - 2*(t & 1)  + (1 - (p & 1));
  wq[i] = f2b(w[(ci*64 + co)*16 + ky*4 + kx]);                // dw2(128,64,4,4)
}

// --------- MFMA implicit-GEMM conv: NHWC in -> NHWC out (64x64 spatial) -----
// M = 32*64*64 = 131072 output positions, block tile 128M x COUT, 4 waves.
// A (im2col) and B (weights [tap][co][ci]) staged per (tap, 32-ci chunk).
template<int CIN,int COUT,int HIN,int S,int KW,int NTAPS,int OSTRIDE,int P,
         bool PARITY,bool RELU,bool INF32,bool OUTF32>
__global__ __launch_bounds__(256) void mconv_k(const void* __restrict__ in_,
    const unsigned short* __restrict__ wq_, const float* __restrict__ bias,
    void* __restrict__ out_) {
  constexpr int NF  = COUT / 16;
  constexpr int NCH = CIN / 32;
  __shared__ short Al[128*40];      // 128 rows x 32 k, stride 40 (80B, 16B-mult)
  __shared__ short Bl[COUT*40];
  int py = 0, px = 0, PY = P, PX = P;
  const unsigned short* wq = wq_;
  if (PARITY) {
    py = blockIdx.y >> 1; px = blockIdx.y & 1;
    PY = 1 - py; PX = 1 - px;
    wq += blockIdx.y * (NTAPS*COUT*CIN);
  }
  const int m0 = blockIdx.x * 128;
  const int w  = threadIdx.x >> 6, l = threadIdx.x & 63;
  const int lm = l & 15, lk = l >> 4;
  f32x4 acc[2][NF];
  #pragma unroll
  for (int mi = 0; mi < 2; ++mi)
    #pragma unroll
    for (int ni = 0; ni < NF; ++ni) acc[mi][ni] = (f32x4)0.0f;

  for (int tap = 0; tap < NTAPS; ++tap) {
    const int ky = tap / KW, kx = tap % KW;
    for (int ch = 0; ch < NCH; ++ch) {
      const int c0 = ch * 32;
      __syncthreads();                       // prev iter frag reads done
      // ---- A stage: 128 rows x 64B, 4 lanes/row ----
      for (int s = threadIdx.x; s < 512; s += 256) {
        const int row = s >> 2, part = s & 3;
        const int m = m0 + row;
        const int n = m >> 12, oy = (m >> 6) & 63, ox = m & 63;
        const int iy = oy*S - PY + ky, ix = ox*S - PX + kx;
        short8 v = (short8)(short)0;
        if (iy >= 0 && iy < HIN && ix >= 0 && ix < HIN) {
          const int base = ((n*HIN + iy)*HIN + ix)*CIN + c0 + part*8;
          if (INF32) {
            const float* pf = (const float*)in_ + base;
            const f32x4 f0 = *(const f32x4*)pf;
            const f32x4 f1 = *(const f32x4*)(pf + 4);
            #pragma unroll
            for (int j = 0; j < 4; ++j) {
              v[j]     = (short)f2b(f0[j]);
              v[j + 4] = (short)f2b(f1[j]);
            }
          } else {
            v = *(const short8*)((const unsigned short*)in_ + base);
          }
        }
        *(short8*)&Al[row*40 + part*8] = v;
      }
      // ---- B stage: COUT rows x 64B ----
      for (int s = threadIdx.x; s < COUT*4; s += 256) {
        const int co = s >> 2, part = s & 3;
        *(short8*)&Bl[co*40 + part*8] =
            *(const short8*)(wq + (tap*COUT + co)*CIN + c0 + part*8);
      }
      __syncthreads();
      // ---- fragments + MFMA ----
      short8 av[2];
      #pragma unroll
      for (int mi = 0; mi < 2; ++mi)
        av[mi] = *(const short8*)&Al[(w*32 + mi*16 + lm)*40 + lk*8];
      #pragma unroll
      for (int ni = 0; ni < NF; ++ni) {
        const short8 bv = *(const short8*)&Bl[(ni*16 + lm)*40 + lk*8];
        #pragma unroll
        for (int mi = 0; mi < 2; ++mi)
          acc[mi][ni] = __builtin_amdgcn_mfma_f32_16x16x32_bf16(
              __builtin_bit_cast(bf16x8, av[mi]),
              __builtin_bit_cast(bf16x8, bv),
              acc[mi][ni], 0, 0, 0);
      }
    }
  }
  // ---- epilogue: C/D layout col=lane&15 (n), row=(lane>>4)*4+reg (m) ----
  #pragma unroll
  for (int ni = 0; ni < NF; ++ni) {
    const int co = ni*16 + lm;
    const float bv = bias[co];
    #pragma unroll
    for (int mi = 0; mi < 2; ++mi) {
      #pragma unroll
      for (int r = 0; r < 4; ++r) {
        const int ml = w*32 + mi*16 + lk*4 + r;
        const int m  = m0 + ml;
        float vv = acc[mi][ni][r] + bv;
        if (RELU) vv = fmaxf(vv, 0.f);
        int off;
        if (OSTRIDE == 1) {
          off = m*COUT + co;
        } else {
          const int n = m >> 12, oy = (m >> 6) & 63, ox = m & 63;
          off = ((n*128 + oy*2 + py)*128 + ox*2 + px)*COUT + co;
        }
        if (OUTF32) ((float*)out_)[off] = vv;
        else ((unsigned short*)out_)[off] = f2b(vv);
      }
    }
  }
}

// ---------------- conv1: x NCHW fp32 (3ch) -> h1 NHWC bf16 [32,128,128,64] --
__global__ __launch_bounds__(256) void conv1_k(const float* __restrict__ x,
    const float* __restrict__ w, const float* __restrict__ bias,
    unsigned short* __restrict__ out) {
  __shared__ float wl[64*48];
  __shared__ float bl[64];
  for (int t = threadIdx.x; t < 3072; t += 256) wl[t] = w[t];
  if (threadIdx.x < 64) bl[threadIdx.x] = bias[threadIdx.x];
  __syncthreads();
  const int n  = blockIdx.x >> 6, oy = (blockIdx.x & 63)*2 + (threadIdx.x >> 7);
  const int ox = threadIdx.x & 127;
  float xin[48];
  #pragma unroll
  for (int ci = 0; ci < 3; ++ci)
    #pragma unroll
    for (int ky = 0; ky < 4; ++ky) {
      const int iy = oy*2 - 1 + ky;
      #pragma unroll
      for (int kx = 0; kx < 4; ++kx) {
        const int ix = ox*2 - 1 + kx;
        float v = 0.f;
        if (iy >= 0 && iy < 256 && ix >= 0 && ix < 256)
          v = x[((n*3 + ci)*256 + iy)*256 + ix];
        xin[ci*16 + ky*4 + kx] = v;
      }
    }
  const int ob = ((n*128 + oy)*128 + ox)*64;
  #pragma unroll
  for (int cb = 0; cb < 8; ++cb) {
    short8 sv;
    #pragma unroll
    for (int j = 0; j < 8; ++j) {
      const int co = cb*8 + j;
      float a = bl[co];
      #pragma unroll
      for (int q = 0; q < 12; ++q) {
        const f32x4 wv = *(const f32x4*)&wl[co*48 + q*4];
        a = fmaf(xin[q*4+0], wv[0], a);
        a = fmaf(xin[q*4+1], wv[1], a);
        a = fmaf(xin[q*4+2], wv[2], a);
        a = fmaf(xin[q*4+3], wv[3], a);
      }
      sv[j] = (short)f2b(fmaxf(a, 0.f));
    }
    *(short8*)&out[ob + cb*8] = sv;
  }
}

// ------- VQ: z fp32 [131072,32] -> zq fp32 [131072,32] + loss partials ------
// 4 points/thread, 128-thread blocks, 256 blocks. Embed chunk transposed
// [c][j] in LDS; inner reads are wave-uniform broadcasts amortized over the
// 4 points -> LDS instr count /4 vs R5. Scan order identical to R5.
__global__ __launch_bounds__(128) void vq_k(const float* __restrict__ z,
    const float* __restrict__ embed, float* __restrict__ zq,
    float* __restrict__ partial) {
  __shared__ float EL[32*256];    // [c][j] transposed chunk (32 KB)
  __shared__ float en[256];
  __shared__ float red[128];
  const int p0 = blockIdx.x*512 + threadIdx.x;      // points p0 + k*128
  f32x4 zf[4][8];
  #pragma unroll
  for (int k = 0; k < 4; ++k)
    #pragma unroll
    for (int c4 = 0; c4 < 8; ++c4)
      zf[k][c4] = *(const f32x4*)&z[(long)(p0 + k*128)*32 + c4*4];
  float best[4]; int bi[4];
  #pragma unroll
  for (int k = 0; k < 4; ++k) { best[k] = 1e30f; bi[k] = 0; }
  for (int chunk = 0; chunk < 2; ++chunk) {
    __syncthreads();
    for (int i = threadIdx.x; i < 8192; i += 128) {
      const int c = i >> 8, j = i & 255;
      EL[c*256 + j] = embed[(chunk*256 + j)*32 + c];
    }
    __syncthreads();
    for (int j = threadIdx.x; j < 256; j += 128) {
      float s = 0.f;
      #pragma unroll
      for (int c = 0; c < 32; ++c)
        s = fmaf(EL[c*256 + j], EL[c*256 + j], s);
      en[j] = s;
    }
    __syncthreads();
    for (int j8 = 0; j8 < 256; j8 += 8) {
      f32x4 dA[4], dB[4];
      #pragma unroll
      for (int k = 0; k < 4; ++k) { dA[k] = (f32x4)0.0f; dB[k] = (f32x4)0.0f; }
      #pragma unroll
      for (int c = 0; c < 32; ++c) {
        const f32x4 eA = *(const f32x4*)&EL[c*256 + j8];
        const f32x4 eB = *(const f32x4*)&EL[c*256 + j8 + 4];
        #pragma unroll
        for (int k = 0; k < 4; ++k) {
          const float zv = zf[k][c >> 2][c & 3];
          dA[k] += eA * zv;
          dB[k] += eB * zv;
        }
      }
      #pragma unroll
      for (int k = 0; k < 4; ++k) {
        #pragma unroll
        for (int e = 0; e < 4; ++e) {
          const float d0 = en[j8 + e] - 2.f*dA[k][e];
          if (d0 < best[k]) { best[k] = d0; bi[k] = chunk*256 + j8 + e; }
        }
        #pragma unroll
        for (int e = 0; e < 4; ++e) {
          const float d1 = en[j8 + 4 + e] - 2.f*dB[k][e];
          if (d1 < best[k]) { best[k] = d1; bi[k] = chunk*256 + j8 + 4 + e; }
        }
      }
    }
  }
  float se = 0.f;
  #pragma unroll
  for (int k = 0; k < 4; ++k) {
    const long pb = (long)(p0 + k*128)*32;
    #pragma unroll
    for (int c4 = 0; c4 < 8; ++c4) {
      const f32x4 ev = *(const f32x4*)&embed[bi[k]*32 + c4*4];  // exact fp32
      *(f32x4*)&zq[pb + c4*4] = ev;
      const f32x4 df = ev - zf[k][c4];
      #pragma unroll
      for (int e = 0; e < 4; ++e) se = fmaf(df[e], df[e], se);
    }
  }
  red[threadIdx.x] = se; __syncthreads();
  for (int s = 64; s > 0; s >>= 1) {
    if (threadIdx.x < s) red[threadIdx.x] += red[threadIdx.x + s];
    __syncthreads();
  }
  if (threadIdx.x == 0) partial[blockIdx.x] = red[0];
}

__global__ __launch_bounds__(256) void loss_k(const float* __restrict__ part,
                                              float* __restrict__ out) {
  __shared__ float red[256];
  const int t = threadIdx.x;
  red[t] = part[t]; __syncthreads();
  for (int s = 128; s > 0; s >>= 1) {
    if (t < s) red[t] += red[t + s];
    __syncthreads();
  }
  if (t == 0) out[0] = red[0] * (1.25f / (131072.f * 32.f));
}

// -------- convt3: d2 NHWC bf16 [32,128,128,64] -> x_recon NCHW fp32 ---------
// block = (n, input-row q, x-half h): output rows 2q,2q+1, cols [h*128,h*128+128).
// IL chunk-major [r][c8][ixl]: inner-loop lane stride = 16B -> conflict-free.
// 37.6 KB LDS -> 4 blocks/CU. Wave = (py,px) uniform -> weight reads broadcast.
__global__ __launch_bounds__(256) void convt3_k(const unsigned short* __restrict__ in,
    const float* __restrict__ w, const float* __restrict__ bias,
    float* __restrict__ out) {
  __shared__ short8 IL[3*8*66];      // [(r*8+c8)*66 + ixl], 25344 B
  __shared__ float  wt[16*192];      // [tap][co][ci] fp32, 12288 B
  const int h = blockIdx.x & 1, q = (blockIdx.x >> 1) & 127, n = blockIdx.x >> 8;
  for (int i = threadIdx.x; i < 3072; i += 256) {
    const int tap = i / 192, rem = i % 192, co = rem >> 6, ci = rem & 63;
    wt[i] = w[(ci*3 + co)*16 + tap];                // dw3 (64,3,4,4)
  }
  // stage 3 input rows x 66 cols (halo +-1), c8 fastest -> coalesced global
  for (int i = threadIdx.x; i < 1584; i += 256) {   // 3*66*8
    const int c8 = i & 7, t = i >> 3, ixl = t % 66, r = t / 66;
    const int iy = q - 1 + r, ix = h*64 - 1 + ixl;
    short8 v = (short8)(short)0;
    if (iy >= 0 && iy < 128 && ix >= 0 && ix < 128)
      v = *(const short8*)(in + (((long)(n*128 + iy)*128 + ix)*64 + c8*8));
    IL[(r*8 + c8)*66 + ixl] = v;
  }
  __syncthreads();
  // wave mapping: px = bit7, py = bit6 (both wave-uniform), xq = lane
  const int px = threadIdx.x >> 7, py = (threadIdx.x >> 6) & 1;
  const int xq = threadIdx.x & 63;
  float acc[3];
  #pragma unroll
  for (int co = 0; co < 3; ++co) acc[co] = bias[co];
  #pragma unroll
  for (int c8 = 0; c8 < 8; ++c8) {
    short8 v[2][2];                                  // [a][b]
    #pragma unroll
    for (int a = 0; a < 2; ++a)
      #pragma unroll
      for (int b = 0; b < 2; ++b)
        v[a][b] = IL[((py + a)*8 + c8)*66 + xq + px + b];
    #pragma unroll
    for (int a = 0; a < 2; ++a) {
      const int ky = 2 - 2*a + (1 - py);
      #pragma unroll
      for (int b = 0; b < 2; ++b) {
        const int kx = 2 - 2*b + (1 - px);
        const int tap = ky*4 + kx;
        float vf[8];
        #pragma unroll
        for (int j = 0; j < 8; ++j) vf[j] = b2f((unsigned short)v[a][b][j]);
        #pragma unroll
        for (int co = 0; co < 3; ++co) {
          const f32x4 w0 = *(const f32x4*)&wt[tap*192 + co*64 + c8*8];
          const f32x4 w1 = *(const f32x4*)&wt[tap*192 + co*64 + c8*8 + 4];
          float a0 = acc[co];
          a0 = fmaf(vf[0], w0[0], a0);
          a0 = fmaf(vf[1], w0[1], a0);
          a0 = fmaf(vf[2], w0[2], a0);
          a0 = fmaf(vf[3], w0[3], a0);
          a0 = fmaf(vf[4], w1[0], a0);
          a0 = fmaf(vf[5], w1[1], a0);
          a0 = fmaf(vf[6], w1[2], a0);
          a0 = fmaf(vf[7], w1[3], a0);
          acc[co] = a0;
        }
      }
    }
  }
  const int oy = 2*q + py, ox = h*128 + 2*xq + px;
  #pragma unroll
  for (int co = 0; co < 3; ++co)
    out[((long)(n*3 + co))*65536 + oy*256 + ox] = acc[co];
}

extern "C" void kernel_launch(void* const* d_in, const int* in_sizes, int n_in,
                              void* d_out, int out_size, void* d_ws, size_t ws_size,
                              hipStream_t stream) {
  const float* x   = (const float*)d_in[0];
  const float* ew1 = (const float*)d_in[1];  const float* eb1 = (const float*)d_in[2];
  const float* ew2 = (const float*)d_in[3];  const float* eb2 = (const float*)d_in[4];
  const float* ew3 = (const float*)d_in[5];  const float* eb3 = (const float*)d_in[6];
  const float* emb = (const float*)d_in[7];
  const float* dw1 = (const float*)d_in[8];  const float* db1 = (const float*)d_in[9];
  const float* dw2 = (const float*)d_in[10]; const float* db2 = (const float*)d_in[11];
  const float* dw3 = (const float*)d_in[12]; const float* db3 = (const float*)d_in[13];
  float* out = (float*)d_out;

  // ws layout (bytes), total 134,219,776:
  //   h1  NHWC bf16 [32,128,128,64]  @ 0          (67108864)   -> reused as d2
  //   h2  NHWC bf16 [32, 64, 64,128] @ 67108864   (33554432)   -> reused as d1
  //   z   f32  [131072,32]           @ 100663296  (16777216)
  //   zq  f32  [131072,32]           @ 117440512  (16777216)
  //   part f32 [256]                 @ 134217728  (1024)
  //   wq2/wq3 overlaid in zq region (dead until vq); wq4/wq5 in z region
  //   (written after vq, when z is dead).
  uint8_t* w8 = (uint8_t*)d_ws;
  unsigned short* h1 = (unsigned short*)w8;
  unsigned short* h2 = (unsigned short*)(w8 + 67108864);
  float* z   = (float*)(w8 + 100663296);
  float* zq  = (float*)(w8 + 117440512);
  float* part = (float*)(w8 + 134217728);
  unsigned short* wq2 = (unsigned short*)(w8 + 117440512);            // 262144 B
  unsigned short* wq3 = (unsigned short*)(w8 + 117440512 + 262144);   // 73728 B
  unsigned short* wq4 = (unsigned short*)(w8 + 100663296);            // 73728 B
  unsigned short* wq5 = (unsigned short*)(w8 + 100663296 + 73728);    // 262144 B
  unsigned short* d1 = h2;
  unsigned short* d2 = h1;

  // encoder weight prep (into zq region, consumed before vq writes zq)
  prep2_k<<<dim3(512),256,0,stream>>>(ew2, wq2);
  prep3_k<<<dim3(144),256,0,stream>>>(ew3, wq3);
  // encoder
  conv1_k<<<dim3(2048),256,0,stream>>>(x, ew1, eb1, h1);
  mconv_k<64,128,128,2,4,16,1,1,false,true,false,false>
      <<<dim3(1024),256,0,stream>>>(h1, wq2, eb2, h2);
  mconv_k<128,32,64,1,3,9,1,1,false,true,false,true>
      <<<dim3(1024),256,0,stream>>>(h2, wq3, eb3, z);
  // VQ + loss
  vq_k<<<dim3(256),128,0,stream>>>(z, emb, zq, part);
  loss_k<<<dim3(1),256,0,stream>>>(part, out + 6291456);
  // decoder weight prep (into z region, dead after vq)
  prep4_k<<<dim3(144),256,0,stream>>>(dw1, wq4);
  prep5_k<<<dim3(512),256,0,stream>>>(dw2, wq5);
  // decoder
  mconv_k<32,128,64,1,3,9,1,1,false,true,true,false>
      <<<dim3(1024),256,0,stream>>>(zq, wq4, db1, d1);
  mconv_k<128,64,64,1,2,4,2,0,true,true,false,false>
      <<<dim3(1024,4),256,0,stream>>>(d1, wq5, db2, d2);
  convt3_k<<<dim3(8192),256,0,stream>>>(d2, dw3, db3, out);
}

// Round 7
// 707.918 us; speedup vs baseline: 1.2326x; 1.2326x over previous
//
#include <hip/hip_runtime.h>

// VQ-VAE forward, MI355X round 7: R5 structure + vq_k at 2 points/thread
// (LDS-issue amortization WITHOUT the R6 register spill). fp32 I/O,
// bf16 intermediates.

typedef __attribute__((ext_vector_type(8))) short     short8;
typedef __attribute__((ext_vector_type(8))) __bf16    bf16x8;
typedef __attribute__((ext_vector_type(4))) float     f32x4;

#define BATCH 32

__device__ __forceinline__ float b2f(unsigned short b) {
  union { unsigned u; float f; } v; v.u = ((unsigned)b) << 16; return v.f;
}
__device__ __forceinline__ unsigned short f2b(float f) {  // round-to-nearest-even
  union { float f; unsigned u; } v; v.f = f;
  unsigned r = v.u + 0x7FFF + ((v.u >> 16) & 1);
  return (unsigned short)(r >> 16);
}

// ---------------- weight prep: reorganize to [tap][co][ci] bf16 -------------
__global__ __launch_bounds__(256) void prep2_k(const float* __restrict__ w,
                                               unsigned short* __restrict__ wq) {
  const int i = blockIdx.x*256 + threadIdx.x;                 // 131072 exact
  const int ci = i & 63, co = (i >> 6) & 127, t = i >> 13;
  wq[i] = f2b(w[(co*64 + ci)*16 + t]);                        // ew2 OIHW(128,64,4,4)
}
__global__ __launch_bounds__(256) void prep3_k(const float* __restrict__ w,
                                               unsigned short* __restrict__ wq) {
  const int i = blockIdx.x*256 + threadIdx.x;                 // 36864 exact
  const int ci = i & 127, co = (i >> 7) & 31, t = i >> 12;
  wq[i] = f2b(w[(co*128 + ci)*9 + t]);                        // ew3 OIHW(32,128,3,3)
}
__global__ __launch_bounds__(256) void prep4_k(const float* __restrict__ w,
                                               unsigned short* __restrict__ wq) {
  const int i = blockIdx.x*256 + threadIdx.x;                 // 36864 exact
  const int ci = i & 31, co = (i >> 5) & 127, t = i >> 12;
  wq[i] = f2b(w[(ci*128 + co)*9 + (8 - t)]);                  // dw1(32,128,3,3), flipped
}
__global__ __launch_bounds__(256) void prep5_k(const float* __restrict__ w,
                                               unsigned short* __restrict__ wq) {
  const int i = blockIdx.x*256 + threadIdx.x;                 // 131072 exact
  const int ci = i & 127, co = (i >> 7) & 63, t = (i >> 13) & 3, p = i >> 15;
  const int ky = 2 - 2*(t >> 1) + (1 - (p >> 1));
  const int kx = 2 - 2*(t & 1)  + (1 - (p & 1));
  wq[i] = f2b(w[(ci*64 + co)*16 + ky*4 + kx]);                // dw2(128,64,4,4)
}

// --------- MFMA implicit-GEMM conv: NHWC in -> NHWC out (64x64 spatial) -----
// M = 32*64*64 = 131072 output positions, block tile 128M x COUT, 4 waves.
// A (im2col) and B (weights [tap][co][ci]) staged per (tap, 32-ci chunk).
template<int CIN,int COUT,int HIN,int S,int KW,int NTAPS,int OSTRIDE,int P,
         bool PARITY,bool RELU,bool INF32,bool OUTF32>
__global__ __launch_bounds__(256) void mconv_k(const void* __restrict__ in_,
    const unsigned short* __restrict__ wq_, const float* __restrict__ bias,
    void* __restrict__ out_) {
  constexpr int NF  = COUT / 16;
  constexpr int NCH = CIN / 32;
  __shared__ short Al[128*40];      // 128 rows x 32 k, stride 40 (80B, 16B-mult)
  __shared__ short Bl[COUT*40];
  int py = 0, px = 0, PY = P, PX = P;
  const unsigned short* wq = wq_;
  if (PARITY) {
    py = blockIdx.y >> 1; px = blockIdx.y & 1;
    PY = 1 - py; PX = 1 - px;
    wq += blockIdx.y * (NTAPS*COUT*CIN);
  }
  const int m0 = blockIdx.x * 128;
  const int w  = threadIdx.x >> 6, l = threadIdx.x & 63;
  const int lm = l & 15, lk = l >> 4;
  f32x4 acc[2][NF];
  #pragma unroll
  for (int mi = 0; mi < 2; ++mi)
    #pragma unroll
    for (int ni = 0; ni < NF; ++ni) acc[mi][ni] = (f32x4)0.0f;

  for (int tap = 0; tap < NTAPS; ++tap) {
    const int ky = tap / KW, kx = tap % KW;
    for (int ch = 0; ch < NCH; ++ch) {
      const int c0 = ch * 32;
      __syncthreads();                       // prev iter frag reads done
      // ---- A stage: 128 rows x 64B, 4 lanes/row ----
      for (int s = threadIdx.x; s < 512; s += 256) {
        const int row = s >> 2, part = s & 3;
        const int m = m0 + row;
        const int n = m >> 12, oy = (m >> 6) & 63, ox = m & 63;
        const int iy = oy*S - PY + ky, ix = ox*S - PX + kx;
        short8 v = (short8)(short)0;
        if (iy >= 0 && iy < HIN && ix >= 0 && ix < HIN) {
          const int base = ((n*HIN + iy)*HIN + ix)*CIN + c0 + part*8;
          if (INF32) {
            const float* pf = (const float*)in_ + base;
            const f32x4 f0 = *(const f32x4*)pf;
            const f32x4 f1 = *(const f32x4*)(pf + 4);
            #pragma unroll
            for (int j = 0; j < 4; ++j) {
              v[j]     = (short)f2b(f0[j]);
              v[j + 4] = (short)f2b(f1[j]);
            }
          } else {
            v = *(const short8*)((const unsigned short*)in_ + base);
          }
        }
        *(short8*)&Al[row*40 + part*8] = v;
      }
      // ---- B stage: COUT rows x 64B ----
      for (int s = threadIdx.x; s < COUT*4; s += 256) {
        const int co = s >> 2, part = s & 3;
        *(short8*)&Bl[co*40 + part*8] =
            *(const short8*)(wq + (tap*COUT + co)*CIN + c0 + part*8);
      }
      __syncthreads();
      // ---- fragments + MFMA ----
      short8 av[2];
      #pragma unroll
      for (int mi = 0; mi < 2; ++mi)
        av[mi] = *(const short8*)&Al[(w*32 + mi*16 + lm)*40 + lk*8];
      #pragma unroll
      for (int ni = 0; ni < NF; ++ni) {
        const short8 bv = *(const short8*)&Bl[(ni*16 + lm)*40 + lk*8];
        #pragma unroll
        for (int mi = 0; mi < 2; ++mi)
          acc[mi][ni] = __builtin_amdgcn_mfma_f32_16x16x32_bf16(
              __builtin_bit_cast(bf16x8, av[mi]),
              __builtin_bit_cast(bf16x8, bv),
              acc[mi][ni], 0, 0, 0);
      }
    }
  }
  // ---- epilogue: C/D layout col=lane&15 (n), row=(lane>>4)*4+reg (m) ----
  #pragma unroll
  for (int ni = 0; ni < NF; ++ni) {
    const int co = ni*16 + lm;
    const float bv = bias[co];
    #pragma unroll
    for (int mi = 0; mi < 2; ++mi) {
      #pragma unroll
      for (int r = 0; r < 4; ++r) {
        const int ml = w*32 + mi*16 + lk*4 + r;
        const int m  = m0 + ml;
        float vv = acc[mi][ni][r] + bv;
        if (RELU) vv = fmaxf(vv, 0.f);
        int off;
        if (OSTRIDE == 1) {
          off = m*COUT + co;
        } else {
          const int n = m >> 12, oy = (m >> 6) & 63, ox = m & 63;
          off = ((n*128 + oy*2 + py)*128 + ox*2 + px)*COUT + co;
        }
        if (OUTF32) ((float*)out_)[off] = vv;
        else ((unsigned short*)out_)[off] = f2b(vv);
      }
    }
  }
}

// ---------------- conv1: x NCHW fp32 (3ch) -> h1 NHWC bf16 [32,128,128,64] --
__global__ __launch_bounds__(256) void conv1_k(const float* __restrict__ x,
    const float* __restrict__ w, const float* __restrict__ bias,
    unsigned short* __restrict__ out) {
  __shared__ float wl[64*48];
  __shared__ float bl[64];
  for (int t = threadIdx.x; t < 3072; t += 256) wl[t] = w[t];
  if (threadIdx.x < 64) bl[threadIdx.x] = bias[threadIdx.x];
  __syncthreads();
  const int n  = blockIdx.x >> 6, oy = (blockIdx.x & 63)*2 + (threadIdx.x >> 7);
  const int ox = threadIdx.x & 127;
  float xin[48];
  #pragma unroll
  for (int ci = 0; ci < 3; ++ci)
    #pragma unroll
    for (int ky = 0; ky < 4; ++ky) {
      const int iy = oy*2 - 1 + ky;
      #pragma unroll
      for (int kx = 0; kx < 4; ++kx) {
        const int ix = ox*2 - 1 + kx;
        float v = 0.f;
        if (iy >= 0 && iy < 256 && ix >= 0 && ix < 256)
          v = x[((n*3 + ci)*256 + iy)*256 + ix];
        xin[ci*16 + ky*4 + kx] = v;
      }
    }
  const int ob = ((n*128 + oy)*128 + ox)*64;
  #pragma unroll
  for (int cb = 0; cb < 8; ++cb) {
    short8 sv;
    #pragma unroll
    for (int j = 0; j < 8; ++j) {
      const int co = cb*8 + j;
      float a = bl[co];
      #pragma unroll
      for (int q = 0; q < 12; ++q) {
        const f32x4 wv = *(const f32x4*)&wl[co*48 + q*4];
        a = fmaf(xin[q*4+0], wv[0], a);
        a = fmaf(xin[q*4+1], wv[1], a);
        a = fmaf(xin[q*4+2], wv[2], a);
        a = fmaf(xin[q*4+3], wv[3], a);
      }
      sv[j] = (short)f2b(fmaxf(a, 0.f));
    }
    *(short8*)&out[ob + cb*8] = sv;
  }
}

// ------- VQ: z fp32 [131072,32] -> zq fp32 [131072,32] + loss partials ------
// 2 points/thread, 256-thread blocks, 256 blocks (~190 VGPR -> no spill).
// Embed chunk transposed [c][j] in LDS; each broadcast read feeds 2 points.
// Scan order per point identical to R5 -> identical argmins.
__global__ __launch_bounds__(256) void vq_k(const float* __restrict__ z,
    const float* __restrict__ embed, float* __restrict__ zq,
    float* __restrict__ partial) {
  __shared__ float EL[32*256];    // [c][j] transposed chunk (32 KB)
  __shared__ float en[256];
  __shared__ float red[256];
  const int p0 = blockIdx.x*512 + threadIdx.x;      // points p0, p0+256
  f32x4 zf[2][8];
  #pragma unroll
  for (int k = 0; k < 2; ++k)
    #pragma unroll
    for (int c4 = 0; c4 < 8; ++c4)
      zf[k][c4] = *(const f32x4*)&z[(long)(p0 + k*256)*32 + c4*4];
  float best[2] = {1e30f, 1e30f}; int bi[2] = {0, 0};
  for (int chunk = 0; chunk < 2; ++chunk) {
    __syncthreads();
    for (int i = threadIdx.x; i < 8192; i += 256) {
      const int c = i >> 8, j = i & 255;
      EL[c*256 + j] = embed[(chunk*256 + j)*32 + c];
    }
    __syncthreads();
    {
      const int j = threadIdx.x;
      float s = 0.f;
      #pragma unroll
      for (int c = 0; c < 32; ++c)
        s = fmaf(EL[c*256 + j], EL[c*256 + j], s);
      en[j] = s;
    }
    __syncthreads();
    for (int j8 = 0; j8 < 256; j8 += 8) {
      f32x4 dA[2], dB[2];
      #pragma unroll
      for (int k = 0; k < 2; ++k) { dA[k] = (f32x4)0.0f; dB[k] = (f32x4)0.0f; }
      #pragma unroll
      for (int c = 0; c < 32; ++c) {
        const f32x4 eA = *(const f32x4*)&EL[c*256 + j8];
        const f32x4 eB = *(const f32x4*)&EL[c*256 + j8 + 4];
        #pragma unroll
        for (int k = 0; k < 2; ++k) {
          const float zv = zf[k][c >> 2][c & 3];
          dA[k] += eA * zv;
          dB[k] += eB * zv;
        }
      }
      #pragma unroll
      for (int k = 0; k < 2; ++k) {
        #pragma unroll
        for (int e = 0; e < 4; ++e) {
          const float d0 = en[j8 + e] - 2.f*dA[k][e];
          if (d0 < best[k]) { best[k] = d0; bi[k] = chunk*256 + j8 + e; }
        }
        #pragma unroll
        for (int e = 0; e < 4; ++e) {
          const float d1 = en[j8 + 4 + e] - 2.f*dB[k][e];
          if (d1 < best[k]) { best[k] = d1; bi[k] = chunk*256 + j8 + 4 + e; }
        }
      }
    }
  }
  float se = 0.f;
  #pragma unroll
  for (int k = 0; k < 2; ++k) {
    const long pb = (long)(p0 + k*256)*32;
    #pragma unroll
    for (int c4 = 0; c4 < 8; ++c4) {
      const f32x4 ev = *(const f32x4*)&embed[bi[k]*32 + c4*4];  // exact fp32
      *(f32x4*)&zq[pb + c4*4] = ev;
      const f32x4 df = ev - zf[k][c4];
      #pragma unroll
      for (int e = 0; e < 4; ++e) se = fmaf(df[e], df[e], se);
    }
  }
  red[threadIdx.x] = se; __syncthreads();
  for (int s = 128; s > 0; s >>= 1) {
    if (threadIdx.x < s) red[threadIdx.x] += red[threadIdx.x + s];
    __syncthreads();
  }
  if (threadIdx.x == 0) partial[blockIdx.x] = red[0];
}

__global__ __launch_bounds__(256) void loss_k(const float* __restrict__ part,
                                              float* __restrict__ out) {
  __shared__ float red[256];
  const int t = threadIdx.x;
  red[t] = part[t]; __syncthreads();
  for (int s = 128; s > 0; s >>= 1) {
    if (t < s) red[t] += red[t + s];
    __syncthreads();
  }
  if (t == 0) out[0] = red[0] * (1.25f / (131072.f * 32.f));
}

// -------- convt3: d2 NHWC bf16 [32,128,128,64] -> x_recon NCHW fp32 ---------
// block = (n, input-row q, x-half h): output rows 2q,2q+1, cols [h*128,h*128+128).
// IL chunk-major [r][c8][ixl]: inner-loop lane stride = 16B -> conflict-free.
// 37.6 KB LDS -> 4 blocks/CU. Wave = (py,px) uniform -> weight reads broadcast.
__global__ __launch_bounds__(256) void convt3_k(const unsigned short* __restrict__ in,
    const float* __restrict__ w, const float* __restrict__ bias,
    float* __restrict__ out) {
  __shared__ short8 IL[3*8*66];      // [(r*8+c8)*66 + ixl], 25344 B
  __shared__ float  wt[16*192];      // [tap][co][ci] fp32, 12288 B
  const int h = blockIdx.x & 1, q = (blockIdx.x >> 1) & 127, n = blockIdx.x >> 8;
  for (int i = threadIdx.x; i < 3072; i += 256) {
    const int tap = i / 192, rem = i % 192, co = rem >> 6, ci = rem & 63;
    wt[i] = w[(ci*3 + co)*16 + tap];                // dw3 (64,3,4,4)
  }
  // stage 3 input rows x 66 cols (halo +-1), c8 fastest -> coalesced global
  for (int i = threadIdx.x; i < 1584; i += 256) {   // 3*66*8
    const int c8 = i & 7, t = i >> 3, ixl = t % 66, r = t / 66;
    const int iy = q - 1 + r, ix = h*64 - 1 + ixl;
    short8 v = (short8)(short)0;
    if (iy >= 0 && iy < 128 && ix >= 0 && ix < 128)
      v = *(const short8*)(in + (((long)(n*128 + iy)*128 + ix)*64 + c8*8));
    IL[(r*8 + c8)*66 + ixl] = v;
  }
  __syncthreads();
  // wave mapping: px = bit7, py = bit6 (both wave-uniform), xq = lane
  const int px = threadIdx.x >> 7, py = (threadIdx.x >> 6) & 1;
  const int xq = threadIdx.x & 63;
  float acc[3];
  #pragma unroll
  for (int co = 0; co < 3; ++co) acc[co] = bias[co];
  #pragma unroll
  for (int c8 = 0; c8 < 8; ++c8) {
    short8 v[2][2];                                  // [a][b]
    #pragma unroll
    for (int a = 0; a < 2; ++a)
      #pragma unroll
      for (int b = 0; b < 2; ++b)
        v[a][b] = IL[((py + a)*8 + c8)*66 + xq + px + b];
    #pragma unroll
    for (int a = 0; a < 2; ++a) {
      const int ky = 2 - 2*a + (1 - py);
      #pragma unroll
      for (int b = 0; b < 2; ++b) {
        const int kx = 2 - 2*b + (1 - px);
        const int tap = ky*4 + kx;
        float vf[8];
        #pragma unroll
        for (int j = 0; j < 8; ++j) vf[j] = b2f((unsigned short)v[a][b][j]);
        #pragma unroll
        for (int co = 0; co < 3; ++co) {
          const f32x4 w0 = *(const f32x4*)&wt[tap*192 + co*64 + c8*8];
          const f32x4 w1 = *(const f32x4*)&wt[tap*192 + co*64 + c8*8 + 4];
          float a0 = acc[co];
          a0 = fmaf(vf[0], w0[0], a0);
          a0 = fmaf(vf[1], w0[1], a0);
          a0 = fmaf(vf[2], w0[2], a0);
          a0 = fmaf(vf[3], w0[3], a0);
          a0 = fmaf(vf[4], w1[0], a0);
          a0 = fmaf(vf[5], w1[1], a0);
          a0 = fmaf(vf[6], w1[2], a0);
          a0 = fmaf(vf[7], w1[3], a0);
          acc[co] = a0;
        }
      }
    }
  }
  const int oy = 2*q + py, ox = h*128 + 2*xq + px;
  #pragma unroll
  for (int co = 0; co < 3; ++co)
    out[((long)(n*3 + co))*65536 + oy*256 + ox] = acc[co];
}

extern "C" void kernel_launch(void* const* d_in, const int* in_sizes, int n_in,
                              void* d_out, int out_size, void* d_ws, size_t ws_size,
                              hipStream_t stream) {
  const float* x   = (const float*)d_in[0];
  const float* ew1 = (const float*)d_in[1];  const float* eb1 = (const float*)d_in[2];
  const float* ew2 = (const float*)d_in[3];  const float* eb2 = (const float*)d_in[4];
  const float* ew3 = (const float*)d_in[5];  const float* eb3 = (const float*)d_in[6];
  const float* emb = (const float*)d_in[7];
  const float* dw1 = (const float*)d_in[8];  const float* db1 = (const float*)d_in[9];
  const float* dw2 = (const float*)d_in[10]; const float* db2 = (const float*)d_in[11];
  const float* dw3 = (const float*)d_in[12]; const float* db3 = (const float*)d_in[13];
  float* out = (float*)d_out;

  // ws layout (bytes), total 134,219,776:
  //   h1  NHWC bf16 [32,128,128,64]  @ 0          (67108864)   -> reused as d2
  //   h2  NHWC bf16 [32, 64, 64,128] @ 67108864   (33554432)   -> reused as d1
  //   z   f32  [131072,32]           @ 100663296  (16777216)
  //   zq  f32  [131072,32]           @ 117440512  (16777216)
  //   part f32 [256]                 @ 134217728  (1024)
  //   wq2/wq3 overlaid in zq region (dead until vq); wq4/wq5 in z region
  //   (written after vq, when z is dead).
  uint8_t* w8 = (uint8_t*)d_ws;
  unsigned short* h1 = (unsigned short*)w8;
  unsigned short* h2 = (unsigned short*)(w8 + 67108864);
  float* z   = (float*)(w8 + 100663296);
  float* zq  = (float*)(w8 + 117440512);
  float* part = (float*)(w8 + 134217728);
  unsigned short* wq2 = (unsigned short*)(w8 + 117440512);            // 262144 B
  unsigned short* wq3 = (unsigned short*)(w8 + 117440512 + 262144);   // 73728 B
  unsigned short* wq4 = (unsigned short*)(w8 + 100663296);            // 73728 B
  unsigned short* wq5 = (unsigned short*)(w8 + 100663296 + 73728);    // 262144 B
  unsigned short* d1 = h2;
  unsigned short* d2 = h1;

  // encoder weight prep (into zq region, consumed before vq writes zq)
  prep2_k<<<dim3(512),256,0,stream>>>(ew2, wq2);
  prep3_k<<<dim3(144),256,0,stream>>>(ew3, wq3);
  // encoder
  conv1_k<<<dim3(2048),256,0,stream>>>(x, ew1, eb1, h1);
  mconv_k<64,128,128,2,4,16,1,1,false,true,false,false>
      <<<dim3(1024),256,0,stream>>>(h1, wq2, eb2, h2);
  mconv_k<128,32,64,1,3,9,1,1,false,true,false,true>
      <<<dim3(1024),256,0,stream>>>(h2, wq3, eb3, z);
  // VQ + loss
  vq_k<<<dim3(256),256,0,stream>>>(z, emb, zq, part);
  loss_k<<<dim3(1),256,0,stream>>>(part, out + 6291456);
  // decoder weight prep (into z region, dead after vq)
  prep4_k<<<dim3(144),256,0,stream>>>(dw1, wq4);
  prep5_k<<<dim3(512),256,0,stream>>>(dw2, wq5);
  // decoder
  mconv_k<32,128,64,1,3,9,1,1,false,true,true,false>
      <<<dim3(1024),256,0,stream>>>(zq, wq4, db1, d1);
  mconv_k<128,64,64,1,2,4,2,0,true,true,false,false>
      <<<dim3(1024,4),256,0,stream>>>(d1, wq5, db2, d2);
  convt3_k<<<dim3(8192),256,0,stream>>>(d2, dw3, db3, out);
}

// Round 10
// 561.008 us; speedup vs baseline: 1.5553x; 1.2619x over previous
//
#include <hip/hip_runtime.h>

// VQ-VAE forward, MI355X round 10: R9 with the loss-partial race fixed —
// partials now live in the h2 region (dead during vqm_k), NOT inside live z.

typedef __attribute__((ext_vector_type(8))) short     short8;
typedef __attribute__((ext_vector_type(4))) short     s16x4;
typedef __attribute__((ext_vector_type(8))) __bf16    bf16x8;
typedef __attribute__((ext_vector_type(4))) float     f32x4;

#define BATCH 32

__device__ __forceinline__ float b2f(unsigned short b) {
  union { unsigned u; float f; } v; v.u = ((unsigned)b) << 16; return v.f;
}
__device__ __forceinline__ unsigned short f2b(float f) {  // round-to-nearest-even
  union { float f; unsigned u; } v; v.f = f;
  unsigned r = v.u + 0x7FFF + ((v.u >> 16) & 1);
  return (unsigned short)(r >> 16);
}

// ---------------- weight prep: reorganize to [tap][co][ci] bf16 -------------
__global__ __launch_bounds__(256) void prep2_k(const float* __restrict__ w,
                                               unsigned short* __restrict__ wq) {
  const int i = blockIdx.x*256 + threadIdx.x;                 // 131072 exact
  const int ci = i & 63, co = (i >> 6) & 127, t = i >> 13;
  wq[i] = f2b(w[(co*64 + ci)*16 + t]);                        // ew2 OIHW(128,64,4,4)
}
__global__ __launch_bounds__(256) void prep3_k(const float* __restrict__ w,
                                               unsigned short* __restrict__ wq) {
  const int i = blockIdx.x*256 + threadIdx.x;                 // 36864 exact
  const int ci = i & 127, co = (i >> 7) & 31, t = i >> 12;
  wq[i] = f2b(w[(co*128 + ci)*9 + t]);                        // ew3 OIHW(32,128,3,3)
}
__global__ __launch_bounds__(256) void prep4_k(const float* __restrict__ w,
                                               unsigned short* __restrict__ wq) {
  const int i = blockIdx.x*256 + threadIdx.x;                 // 36864 exact
  const int ci = i & 31, co = (i >> 5) & 127, t = i >> 12;
  wq[i] = f2b(w[(ci*128 + co)*9 + (8 - t)]);                  // dw1(32,128,3,3), flipped
}
__global__ __launch_bounds__(256) void prep5_k(const float* __restrict__ w,
                                               unsigned short* __restrict__ wq) {
  const int i = blockIdx.x*256 + threadIdx.x;                 // 131072 exact
  const int ci = i & 127, co = (i >> 7) & 63, t = (i >> 13) & 3, p = i >> 15;
  const int ky = 2 - 2*(t >> 1) + (1 - (p >> 1));
  const int kx = 2 - 2*(t & 1)  + (1 - (p & 1));
  wq[i] = f2b(w[(ci*64 + co)*16 + ky*4 + kx]);                // dw2(128,64,4,4)
}

// --------- MFMA implicit-GEMM conv: NHWC in -> NHWC out (64x64 spatial) -----
template<int CIN,int COUT,int HIN,int S,int KW,int NTAPS,int OSTRIDE,int P,
         bool PARITY,bool RELU,bool INF32,bool OUTF32>
__global__ __launch_bounds__(256) void mconv_k(const void* __restrict__ in_,
    const unsigned short* __restrict__ wq_, const float* __restrict__ bias,
    void* __restrict__ out_) {
  constexpr int NF  = COUT / 16;
  constexpr int NCH = CIN / 32;
  __shared__ short Al[128*40];      // 128 rows x 32 k, stride 40 (80B, 16B-mult)
  __shared__ short Bl[COUT*40];
  int py = 0, px = 0, PY = P, PX = P;
  const unsigned short* wq = wq_;
  if (PARITY) {
    py = blockIdx.y >> 1; px = blockIdx.y & 1;
    PY = 1 - py; PX = 1 - px;
    wq += blockIdx.y * (NTAPS*COUT*CIN);
  }
  const int m0 = blockIdx.x * 128;
  const int w  = threadIdx.x >> 6, l = threadIdx.x & 63;
  const int lm = l & 15, lk = l >> 4;
  f32x4 acc[2][NF];
  #pragma unroll
  for (int mi = 0; mi < 2; ++mi)
    #pragma unroll
    for (int ni = 0; ni < NF; ++ni) acc[mi][ni] = (f32x4)0.0f;

  for (int tap = 0; tap < NTAPS; ++tap) {
    const int ky = tap / KW, kx = tap % KW;
    for (int ch = 0; ch < NCH; ++ch) {
      const int c0 = ch * 32;
      __syncthreads();                       // prev iter frag reads done
      for (int s = threadIdx.x; s < 512; s += 256) {
        const int row = s >> 2, part = s & 3;
        const int m = m0 + row;
        const int n = m >> 12, oy = (m >> 6) & 63, ox = m & 63;
        const int iy = oy*S - PY + ky, ix = ox*S - PX + kx;
        short8 v = (short8)(short)0;
        if (iy >= 0 && iy < HIN && ix >= 0 && ix < HIN) {
          const int base = ((n*HIN + iy)*HIN + ix)*CIN + c0 + part*8;
          if (INF32) {
            const float* pf = (const float*)in_ + base;
            const f32x4 f0 = *(const f32x4*)pf;
            const f32x4 f1 = *(const f32x4*)(pf + 4);
            #pragma unroll
            for (int j = 0; j < 4; ++j) {
              v[j]     = (short)f2b(f0[j]);
              v[j + 4] = (short)f2b(f1[j]);
            }
          } else {
            v = *(const short8*)((const unsigned short*)in_ + base);
          }
        }
        *(short8*)&Al[row*40 + part*8] = v;
      }
      for (int s = threadIdx.x; s < COUT*4; s += 256) {
        const int co = s >> 2, part = s & 3;
        *(short8*)&Bl[co*40 + part*8] =
            *(const short8*)(wq + (tap*COUT + co)*CIN + c0 + part*8);
      }
      __syncthreads();
      short8 av[2];
      #pragma unroll
      for (int mi = 0; mi < 2; ++mi)
        av[mi] = *(const short8*)&Al[(w*32 + mi*16 + lm)*40 + lk*8];
      #pragma unroll
      for (int ni = 0; ni < NF; ++ni) {
        const short8 bv = *(const short8*)&Bl[(ni*16 + lm)*40 + lk*8];
        #pragma unroll
        for (int mi = 0; mi < 2; ++mi)
          acc[mi][ni] = __builtin_amdgcn_mfma_f32_16x16x32_bf16(
              __builtin_bit_cast(bf16x8, av[mi]),
              __builtin_bit_cast(bf16x8, bv),
              acc[mi][ni], 0, 0, 0);
      }
    }
  }
  #pragma unroll
  for (int ni = 0; ni < NF; ++ni) {
    const int co = ni*16 + lm;
    const float bv = bias[co];
    #pragma unroll
    for (int mi = 0; mi < 2; ++mi) {
      #pragma unroll
      for (int r = 0; r < 4; ++r) {
        const int ml = w*32 + mi*16 + lk*4 + r;
        const int m  = m0 + ml;
        float vv = acc[mi][ni][r] + bv;
        if (RELU) vv = fmaxf(vv, 0.f);
        int off;
        if (OSTRIDE == 1) {
          off = m*COUT + co;
        } else {
          const int n = m >> 12, oy = (m >> 6) & 63, ox = m & 63;
          off = ((n*128 + oy*2 + py)*128 + ox*2 + px)*COUT + co;
        }
        if (OUTF32) ((float*)out_)[off] = vv;
        else ((unsigned short*)out_)[off] = f2b(vv);
      }
    }
  }
}

// ---------------- conv1: x NCHW fp32 (3ch) -> h1 NHWC bf16 [32,128,128,64] --
__global__ __launch_bounds__(256) void conv1_k(const float* __restrict__ x,
    const float* __restrict__ w, const float* __restrict__ bias,
    unsigned short* __restrict__ out) {
  __shared__ float wl[64*48];
  __shared__ float bl[64];
  for (int t = threadIdx.x; t < 3072; t += 256) wl[t] = w[t];
  if (threadIdx.x < 64) bl[threadIdx.x] = bias[threadIdx.x];
  __syncthreads();
  const int n  = blockIdx.x >> 6, oy = (blockIdx.x & 63)*2 + (threadIdx.x >> 7);
  const int ox = threadIdx.x & 127;
  float xin[48];
  #pragma unroll
  for (int ci = 0; ci < 3; ++ci)
    #pragma unroll
    for (int ky = 0; ky < 4; ++ky) {
      const int iy = oy*2 - 1 + ky;
      #pragma unroll
      for (int kx = 0; kx < 4; ++kx) {
        const int ix = ox*2 - 1 + kx;
        float v = 0.f;
        if (iy >= 0 && iy < 256 && ix >= 0 && ix < 256)
          v = x[((n*3 + ci)*256 + iy)*256 + ix];
        xin[ci*16 + ky*4 + kx] = v;
      }
    }
  const int ob = ((n*128 + oy)*128 + ox)*64;
  #pragma unroll
  for (int cb = 0; cb < 8; ++cb) {
    short8 sv;
    #pragma unroll
    for (int j = 0; j < 8; ++j) {
      const int co = cb*8 + j;
      float a = bl[co];
      #pragma unroll
      for (int q = 0; q < 12; ++q) {
        const f32x4 wv = *(const f32x4*)&wl[co*48 + q*4];
        a = fmaf(xin[q*4+0], wv[0], a);
        a = fmaf(xin[q*4+1], wv[1], a);
        a = fmaf(xin[q*4+2], wv[2], a);
        a = fmaf(xin[q*4+3], wv[3], a);
      }
      sv[j] = (short)f2b(fmaxf(a, 0.f));
    }
    *(short8*)&out[ob + cb*8] = sv;
  }
}

// ------- VQ via MFMA: z fp32 [131072,32] -> zq fp32 + loss partials ---------
// Block = 128 points. dot = z@e^T on matrix cores (bf16 in, fp32 out);
// d = |e|^2 - 2 dot compared in fp32; argmin first-min semantics preserved
// (ascending per-lane scan + lexicographic cross-lane reduce). Gathered
// codewords + SSE use exact fp32 embed from global.
__global__ __launch_bounds__(256) void vqm_k(const float* __restrict__ z,
    const float* __restrict__ embed, float* __restrict__ zq,
    float* __restrict__ partial) {
  __shared__ short Be[512*40];     // bf16 codes, pad stride 40 (40960 B)
  __shared__ float en[512];        // |e|^2 (bf16-rounded e), fp32
  __shared__ int   bidx[128];
  __shared__ float red[256];
  const int m0 = blockIdx.x * 128;
  // stage embed -> bf16 LDS (coalesced f32x4 reads)
  for (int i = threadIdx.x; i < 4096; i += 256) {
    const int j = i >> 3, k0 = (i & 7) * 4;
    const f32x4 v = *(const f32x4*)&embed[j*32 + k0];
    s16x4 s;
    #pragma unroll
    for (int e = 0; e < 4; ++e) s[e] = (short)f2b(v[e]);
    *(s16x4*)&Be[j*40 + k0] = s;
  }
  __syncthreads();
  for (int j = threadIdx.x; j < 512; j += 256) {
    float s = 0.f;
    #pragma unroll
    for (int q = 0; q < 4; ++q) {
      const short8 v = *(const short8*)&Be[j*40 + q*8];
      #pragma unroll
      for (int e = 0; e < 8; ++e) {
        const float f = b2f((unsigned short)v[e]);
        s = fmaf(f, f, s);
      }
    }
    en[j] = s;
  }
  __syncthreads();
  const int w = threadIdx.x >> 6, l = threadIdx.x & 63;
  const int lm = l & 15, lk = l >> 4;
  const int rw = w * 32;
  // A fragments straight from global z (16 consecutive rows/frag: coalesced)
  short8 av[2];
  #pragma unroll
  for (int mi = 0; mi < 2; ++mi) {
    const float* zp = z + (long)(m0 + rw + mi*16 + lm)*32 + lk*8;
    const f32x4 f0 = *(const f32x4*)zp;
    const f32x4 f1 = *(const f32x4*)(zp + 4);
    short8 v;
    #pragma unroll
    for (int e = 0; e < 4; ++e) {
      v[e]     = (short)f2b(f0[e]);
      v[e + 4] = (short)f2b(f1[e]);
    }
    av[mi] = v;
  }
  float bd[2][4]; int bj[2][4];
  #pragma unroll
  for (int mi = 0; mi < 2; ++mi)
    #pragma unroll
    for (int r = 0; r < 4; ++r) { bd[mi][r] = 1e30f; bj[mi][r] = 0; }
  for (int nc = 0; nc < 8; ++nc) {               // N-chunks of 64 codes
    f32x4 acc[2][4];
    #pragma unroll
    for (int mi = 0; mi < 2; ++mi)
      #pragma unroll
      for (int ni = 0; ni < 4; ++ni) acc[mi][ni] = (f32x4)0.0f;
    #pragma unroll
    for (int ni = 0; ni < 4; ++ni) {
      const short8 bv = *(const short8*)&Be[(nc*64 + ni*16 + lm)*40 + lk*8];
      #pragma unroll
      for (int mi = 0; mi < 2; ++mi)
        acc[mi][ni] = __builtin_amdgcn_mfma_f32_16x16x32_bf16(
            __builtin_bit_cast(bf16x8, av[mi]),
            __builtin_bit_cast(bf16x8, bv),
            acc[mi][ni], 0, 0, 0);
    }
    #pragma unroll
    for (int ni = 0; ni < 4; ++ni) {
      const int j = nc*64 + ni*16 + lm;          // lane's code column
      const float e_n = en[j];
      #pragma unroll
      for (int mi = 0; mi < 2; ++mi)
        #pragma unroll
        for (int r = 0; r < 4; ++r) {
          const float d = fmaf(-2.f, acc[mi][ni][r], e_n);
          if (d < bd[mi][r]) { bd[mi][r] = d; bj[mi][r] = j; }
        }
    }
  }
  // cross-lane first-min reduce over the 16 lanes sharing a row group
  #pragma unroll
  for (int mi = 0; mi < 2; ++mi)
    #pragma unroll
    for (int r = 0; r < 4; ++r) {
      float d = bd[mi][r]; int j = bj[mi][r];
      #pragma unroll
      for (int off = 1; off < 16; off <<= 1) {
        const float od = __shfl_xor(d, off);
        const int   oj = __shfl_xor(j, off);
        if (od < d || (od == d && oj < j)) { d = od; j = oj; }
      }
      if (lm == 0) bidx[rw + mi*16 + lk*4 + r] = j;
    }
  __syncthreads();
  // epilogue: exact fp32 gather + zq write + SSE
  const int pl = threadIdx.x >> 1, hf = (threadIdx.x & 1) * 16;
  const int code = bidx[pl];
  const long pb = (long)(m0 + pl)*32 + hf;
  float se = 0.f;
  #pragma unroll
  for (int q = 0; q < 4; ++q) {
    const f32x4 ev = *(const f32x4*)&embed[code*32 + hf + q*4];
    const f32x4 zv = *(const f32x4*)&z[pb + q*4];
    *(f32x4*)&zq[pb + q*4] = ev;
    const f32x4 df = ev - zv;
    #pragma unroll
    for (int e = 0; e < 4; ++e) se = fmaf(df[e], df[e], se);
  }
  red[threadIdx.x] = se; __syncthreads();
  for (int s = 128; s > 0; s >>= 1) {
    if (threadIdx.x < s) red[threadIdx.x] += red[threadIdx.x + s];
    __syncthreads();
  }
  if (threadIdx.x == 0) partial[blockIdx.x] = red[0];
}

__global__ __launch_bounds__(256) void loss_k(const float* __restrict__ part,
                                              float* __restrict__ out) {
  __shared__ float red[256];
  const int t = threadIdx.x;
  float s = 0.f;
  #pragma unroll
  for (int q = 0; q < 4; ++q) s += part[t + q*256];   // 1024 partials
  red[t] = s; __syncthreads();
  for (int st = 128; st > 0; st >>= 1) {
    if (t < st) red[t] += red[t + st];
    __syncthreads();
  }
  if (t == 0) out[0] = red[0] * (1.25f / (131072.f * 32.f));
}

// -------- convt3: d2 NHWC bf16 [32,128,128,64] -> x_recon NCHW fp32 ---------
__global__ __launch_bounds__(256) void convt3_k(const unsigned short* __restrict__ in,
    const float* __restrict__ w, const float* __restrict__ bias,
    float* __restrict__ out) {
  __shared__ short8 IL[3*8*66];      // [(r*8+c8)*66 + ixl], 25344 B
  __shared__ float  wt[16*192];      // [tap][co][ci] fp32, 12288 B
  const int h = blockIdx.x & 1, q = (blockIdx.x >> 1) & 127, n = blockIdx.x >> 8;
  for (int i = threadIdx.x; i < 3072; i += 256) {
    const int tap = i / 192, rem = i % 192, co = rem >> 6, ci = rem & 63;
    wt[i] = w[(ci*3 + co)*16 + tap];                // dw3 (64,3,4,4)
  }
  for (int i = threadIdx.x; i < 1584; i += 256) {   // 3*66*8
    const int c8 = i & 7, t = i >> 3, ixl = t % 66, r = t / 66;
    const int iy = q - 1 + r, ix = h*64 - 1 + ixl;
    short8 v = (short8)(short)0;
    if (iy >= 0 && iy < 128 && ix >= 0 && ix < 128)
      v = *(const short8*)(in + (((long)(n*128 + iy)*128 + ix)*64 + c8*8));
    IL[(r*8 + c8)*66 + ixl] = v;
  }
  __syncthreads();
  const int px = threadIdx.x >> 7, py = (threadIdx.x >> 6) & 1;
  const int xq = threadIdx.x & 63;
  float acc[3];
  #pragma unroll
  for (int co = 0; co < 3; ++co) acc[co] = bias[co];
  #pragma unroll
  for (int c8 = 0; c8 < 8; ++c8) {
    short8 v[2][2];
    #pragma unroll
    for (int a = 0; a < 2; ++a)
      #pragma unroll
      for (int b = 0; b < 2; ++b)
        v[a][b] = IL[((py + a)*8 + c8)*66 + xq + px + b];
    #pragma unroll
    for (int a = 0; a < 2; ++a) {
      const int ky = 2 - 2*a + (1 - py);
      #pragma unroll
      for (int b = 0; b < 2; ++b) {
        const int kx = 2 - 2*b + (1 - px);
        const int tap = ky*4 + kx;
        float vf[8];
        #pragma unroll
        for (int j = 0; j < 8; ++j) vf[j] = b2f((unsigned short)v[a][b][j]);
        #pragma unroll
        for (int co = 0; co < 3; ++co) {
          const f32x4 w0 = *(const f32x4*)&wt[tap*192 + co*64 + c8*8];
          const f32x4 w1 = *(const f32x4*)&wt[tap*192 + co*64 + c8*8 + 4];
          float a0 = acc[co];
          a0 = fmaf(vf[0], w0[0], a0);
          a0 = fmaf(vf[1], w0[1], a0);
          a0 = fmaf(vf[2], w0[2], a0);
          a0 = fmaf(vf[3], w0[3], a0);
          a0 = fmaf(vf[4], w1[0], a0);
          a0 = fmaf(vf[5], w1[1], a0);
          a0 = fmaf(vf[6], w1[2], a0);
          a0 = fmaf(vf[7], w1[3], a0);
          acc[co] = a0;
        }
      }
    }
  }
  const int oy = 2*q + py, ox = h*128 + 2*xq + px;
  #pragma unroll
  for (int co = 0; co < 3; ++co)
    out[((long)(n*3 + co))*65536 + oy*256 + ox] = acc[co];
}

extern "C" void kernel_launch(void* const* d_in, const int* in_sizes, int n_in,
                              void* d_out, int out_size, void* d_ws, size_t ws_size,
                              hipStream_t stream) {
  const float* x   = (const float*)d_in[0];
  const float* ew1 = (const float*)d_in[1];  const float* eb1 = (const float*)d_in[2];
  const float* ew2 = (const float*)d_in[3];  const float* eb2 = (const float*)d_in[4];
  const float* ew3 = (const float*)d_in[5];  const float* eb3 = (const float*)d_in[6];
  const float* emb = (const float*)d_in[7];
  const float* dw1 = (const float*)d_in[8];  const float* db1 = (const float*)d_in[9];
  const float* dw2 = (const float*)d_in[10]; const float* db2 = (const float*)d_in[11];
  const float* dw3 = (const float*)d_in[12]; const float* db3 = (const float*)d_in[13];
  float* out = (float*)d_out;

  // ws layout (bytes), total 134,217,728:
  //   h1  NHWC bf16 [32,128,128,64]  @ 0          (67108864)   -> reused as d2
  //   h2  NHWC bf16 [32, 64, 64,128] @ 67108864   (33554432)   -> reused as d1
  //   z   f32  [131072,32]           @ 100663296  (16777216)
  //   zq  f32  [131072,32]           @ 117440512  (16777216)
  //   loss partials (1024 f32, 4 KB) @ 67108864 — h2 region, which is DEAD
  //     during vqm_k (conv3 consumed it; d1 overwrites only after loss_k).
  //     NOTE (R9 post-mortem): placing partials inside z raced with vqm_k's
  //     own z reads — z is live for the whole vqm_k dispatch.
  //   wq2/wq3 overlaid in zq region (dead until vqm writes zq);
  //   wq4/wq5 overlaid in z region (written after vqm, z dead then).
  uint8_t* w8 = (uint8_t*)d_ws;
  unsigned short* h1 = (unsigned short*)w8;
  unsigned short* h2 = (unsigned short*)(w8 + 67108864);
  float* z   = (float*)(w8 + 100663296);
  float* zq  = (float*)(w8 + 117440512);
  float* part = (float*)(w8 + 67108864);              // h2 region (dead @ vqm)
  unsigned short* wq2 = (unsigned short*)(w8 + 117440512);            // 262144 B
  unsigned short* wq3 = (unsigned short*)(w8 + 117440512 + 262144);   // 73728 B
  unsigned short* wq4 = (unsigned short*)(w8 + 100663296);            // 73728 B
  unsigned short* wq5 = (unsigned short*)(w8 + 100663296 + 73728);    // 262144 B
  unsigned short* d1 = h2;
  unsigned short* d2 = h1;

  // encoder weight prep (into zq region, consumed before vqm writes zq)
  prep2_k<<<dim3(512),256,0,stream>>>(ew2, wq2);
  prep3_k<<<dim3(144),256,0,stream>>>(ew3, wq3);
  // encoder
  conv1_k<<<dim3(2048),256,0,stream>>>(x, ew1, eb1, h1);
  mconv_k<64,128,128,2,4,16,1,1,false,true,false,false>
      <<<dim3(1024),256,0,stream>>>(h1, wq2, eb2, h2);
  mconv_k<128,32,64,1,3,9,1,1,false,true,false,true>
      <<<dim3(1024),256,0,stream>>>(h2, wq3, eb3, z);
  // VQ (MFMA) + loss  (partials in h2 region; loss_k consumes before d1 write)
  vqm_k<<<dim3(1024),256,0,stream>>>(z, emb, zq, part);
  loss_k<<<dim3(1),256,0,stream>>>(part, out + 6291456);
  // decoder weight prep (into z region, dead after vqm)
  prep4_k<<<dim3(144),256,0,stream>>>(dw1, wq4);
  prep5_k<<<dim3(512),256,0,stream>>>(dw2, wq5);
  // decoder
  mconv_k<32,128,64,1,3,9,1,1,false,true,true,false>
      <<<dim3(1024),256,0,stream>>>(zq, wq4, db1, d1);
  mconv_k<128,64,64,1,2,4,2,0,true,true,false,false>
      <<<dim3(1024,4),256,0,stream>>>(d1, wq5, db2, d2);
  convt3_k<<<dim3(8192),256,0,stream>>>(d2, dw3, db3, out);
}

// Round 11
// 508.451 us; speedup vs baseline: 1.7161x; 1.1034x over previous
//
#include <hip/hip_runtime.h>

// VQ-VAE forward, MI355X round 11: R10 + convt3 moved onto matrix cores
// (per-wave parity GEMM, M=64 N=16(3 used) K=256). fp32 I/O, bf16 inters.

typedef __attribute__((ext_vector_type(8))) short     short8;
typedef __attribute__((ext_vector_type(4))) short     s16x4;
typedef __attribute__((ext_vector_type(8))) __bf16    bf16x8;
typedef __attribute__((ext_vector_type(4))) float     f32x4;

#define BATCH 32

__device__ __forceinline__ float b2f(unsigned short b) {
  union { unsigned u; float f; } v; v.u = ((unsigned)b) << 16; return v.f;
}
__device__ __forceinline__ unsigned short f2b(float f) {  // round-to-nearest-even
  union { float f; unsigned u; } v; v.f = f;
  unsigned r = v.u + 0x7FFF + ((v.u >> 16) & 1);
  return (unsigned short)(r >> 16);
}

// ---------------- weight prep: reorganize to [tap][co][ci] bf16 -------------
__global__ __launch_bounds__(256) void prep2_k(const float* __restrict__ w,
                                               unsigned short* __restrict__ wq) {
  const int i = blockIdx.x*256 + threadIdx.x;                 // 131072 exact
  const int ci = i & 63, co = (i >> 6) & 127, t = i >> 13;
  wq[i] = f2b(w[(co*64 + ci)*16 + t]);                        // ew2 OIHW(128,64,4,4)
}
__global__ __launch_bounds__(256) void prep3_k(const float* __restrict__ w,
                                               unsigned short* __restrict__ wq) {
  const int i = blockIdx.x*256 + threadIdx.x;                 // 36864 exact
  const int ci = i & 127, co = (i >> 7) & 31, t = i >> 12;
  wq[i] = f2b(w[(co*128 + ci)*9 + t]);                        // ew3 OIHW(32,128,3,3)
}
__global__ __launch_bounds__(256) void prep4_k(const float* __restrict__ w,
                                               unsigned short* __restrict__ wq) {
  const int i = blockIdx.x*256 + threadIdx.x;                 // 36864 exact
  const int ci = i & 31, co = (i >> 5) & 127, t = i >> 12;
  wq[i] = f2b(w[(ci*128 + co)*9 + (8 - t)]);                  // dw1(32,128,3,3), flipped
}
__global__ __launch_bounds__(256) void prep5_k(const float* __restrict__ w,
                                               unsigned short* __restrict__ wq) {
  const int i = blockIdx.x*256 + threadIdx.x;                 // 131072 exact
  const int ci = i & 127, co = (i >> 7) & 63, t = (i >> 13) & 3, p = i >> 15;
  const int ky = 2 - 2*(t >> 1) + (1 - (p >> 1));
  const int kx = 2 - 2*(t & 1)  + (1 - (p & 1));
  wq[i] = f2b(w[(ci*64 + co)*16 + ky*4 + kx]);                // dw2(128,64,4,4)
}
// convt3 B-frags: wq6[p][kc][lane l][j] = w[tap(a,b,p)][ci=(kc&1)*32+lk*8+j][co=lm]
__global__ __launch_bounds__(256) void prep6_k(const float* __restrict__ w,
                                               unsigned short* __restrict__ wq) {
  const int i = blockIdx.x*256 + threadIdx.x;                 // 16384 exact
  const int j = i & 7, l = (i >> 3) & 63, kc = (i >> 9) & 7, p = i >> 12;
  const int lm = l & 15, lk = l >> 4;
  const int a = kc >> 2, b = (kc >> 1) & 1, ch = kc & 1;
  const int ci = ch*32 + lk*8 + j, co = lm;
  const int py = p >> 1, px = p & 1;
  const int ky = 2 - 2*a + (1 - py), kx = 2 - 2*b + (1 - px);
  wq[i] = (co < 3) ? f2b(w[(ci*3 + co)*16 + ky*4 + kx]) : (unsigned short)0;
}

// --------- MFMA implicit-GEMM conv: NHWC in -> NHWC out (64x64 spatial) -----
template<int CIN,int COUT,int HIN,int S,int KW,int NTAPS,int OSTRIDE,int P,
         bool PARITY,bool RELU,bool INF32,bool OUTF32>
__global__ __launch_bounds__(256) void mconv_k(const void* __restrict__ in_,
    const unsigned short* __restrict__ wq_, const float* __restrict__ bias,
    void* __restrict__ out_) {
  constexpr int NF  = COUT / 16;
  constexpr int NCH = CIN / 32;
  __shared__ short Al[128*40];      // 128 rows x 32 k, stride 40 (80B, 16B-mult)
  __shared__ short Bl[COUT*40];
  int py = 0, px = 0, PY = P, PX = P;
  const unsigned short* wq = wq_;
  if (PARITY) {
    py = blockIdx.y >> 1; px = blockIdx.y & 1;
    PY = 1 - py; PX = 1 - px;
    wq += blockIdx.y * (NTAPS*COUT*CIN);
  }
  const int m0 = blockIdx.x * 128;
  const int w  = threadIdx.x >> 6, l = threadIdx.x & 63;
  const int lm = l & 15, lk = l >> 4;
  f32x4 acc[2][NF];
  #pragma unroll
  for (int mi = 0; mi < 2; ++mi)
    #pragma unroll
    for (int ni = 0; ni < NF; ++ni) acc[mi][ni] = (f32x4)0.0f;

  for (int tap = 0; tap < NTAPS; ++tap) {
    const int ky = tap / KW, kx = tap % KW;
    for (int ch = 0; ch < NCH; ++ch) {
      const int c0 = ch * 32;
      __syncthreads();                       // prev iter frag reads done
      for (int s = threadIdx.x; s < 512; s += 256) {
        const int row = s >> 2, part = s & 3;
        const int m = m0 + row;
        const int n = m >> 12, oy = (m >> 6) & 63, ox = m & 63;
        const int iy = oy*S - PY + ky, ix = ox*S - PX + kx;
        short8 v = (short8)(short)0;
        if (iy >= 0 && iy < HIN && ix >= 0 && ix < HIN) {
          const int base = ((n*HIN + iy)*HIN + ix)*CIN + c0 + part*8;
          if (INF32) {
            const float* pf = (const float*)in_ + base;
            const f32x4 f0 = *(const f32x4*)pf;
            const f32x4 f1 = *(const f32x4*)(pf + 4);
            #pragma unroll
            for (int j = 0; j < 4; ++j) {
              v[j]     = (short)f2b(f0[j]);
              v[j + 4] = (short)f2b(f1[j]);
            }
          } else {
            v = *(const short8*)((const unsigned short*)in_ + base);
          }
        }
        *(short8*)&Al[row*40 + part*8] = v;
      }
      for (int s = threadIdx.x; s < COUT*4; s += 256) {
        const int co = s >> 2, part = s & 3;
        *(short8*)&Bl[co*40 + part*8] =
            *(const short8*)(wq + (tap*COUT + co)*CIN + c0 + part*8);
      }
      __syncthreads();
      short8 av[2];
      #pragma unroll
      for (int mi = 0; mi < 2; ++mi)
        av[mi] = *(const short8*)&Al[(w*32 + mi*16 + lm)*40 + lk*8];
      #pragma unroll
      for (int ni = 0; ni < NF; ++ni) {
        const short8 bv = *(const short8*)&Bl[(ni*16 + lm)*40 + lk*8];
        #pragma unroll
        for (int mi = 0; mi < 2; ++mi)
          acc[mi][ni] = __builtin_amdgcn_mfma_f32_16x16x32_bf16(
              __builtin_bit_cast(bf16x8, av[mi]),
              __builtin_bit_cast(bf16x8, bv),
              acc[mi][ni], 0, 0, 0);
      }
    }
  }
  #pragma unroll
  for (int ni = 0; ni < NF; ++ni) {
    const int co = ni*16 + lm;
    const float bv = bias[co];
    #pragma unroll
    for (int mi = 0; mi < 2; ++mi) {
      #pragma unroll
      for (int r = 0; r < 4; ++r) {
        const int ml = w*32 + mi*16 + lk*4 + r;
        const int m  = m0 + ml;
        float vv = acc[mi][ni][r] + bv;
        if (RELU) vv = fmaxf(vv, 0.f);
        int off;
        if (OSTRIDE == 1) {
          off = m*COUT + co;
        } else {
          const int n = m >> 12, oy = (m >> 6) & 63, ox = m & 63;
          off = ((n*128 + oy*2 + py)*128 + ox*2 + px)*COUT + co;
        }
        if (OUTF32) ((float*)out_)[off] = vv;
        else ((unsigned short*)out_)[off] = f2b(vv);
      }
    }
  }
}

// ---------------- conv1: x NCHW fp32 (3ch) -> h1 NHWC bf16 [32,128,128,64] --
__global__ __launch_bounds__(256) void conv1_k(const float* __restrict__ x,
    const float* __restrict__ w, const float* __restrict__ bias,
    unsigned short* __restrict__ out) {
  __shared__ float wl[64*48];
  __shared__ float bl[64];
  for (int t = threadIdx.x; t < 3072; t += 256) wl[t] = w[t];
  if (threadIdx.x < 64) bl[threadIdx.x] = bias[threadIdx.x];
  __syncthreads();
  const int n  = blockIdx.x >> 6, oy = (blockIdx.x & 63)*2 + (threadIdx.x >> 7);
  const int ox = threadIdx.x & 127;
  float xin[48];
  #pragma unroll
  for (int ci = 0; ci < 3; ++ci)
    #pragma unroll
    for (int ky = 0; ky < 4; ++ky) {
      const int iy = oy*2 - 1 + ky;
      #pragma unroll
      for (int kx = 0; kx < 4; ++kx) {
        const int ix = ox*2 - 1 + kx;
        float v = 0.f;
        if (iy >= 0 && iy < 256 && ix >= 0 && ix < 256)
          v = x[((n*3 + ci)*256 + iy)*256 + ix];
        xin[ci*16 + ky*4 + kx] = v;
      }
    }
  const int ob = ((n*128 + oy)*128 + ox)*64;
  #pragma unroll
  for (int cb = 0; cb < 8; ++cb) {
    short8 sv;
    #pragma unroll
    for (int j = 0; j < 8; ++j) {
      const int co = cb*8 + j;
      float a = bl[co];
      #pragma unroll
      for (int q = 0; q < 12; ++q) {
        const f32x4 wv = *(const f32x4*)&wl[co*48 + q*4];
        a = fmaf(xin[q*4+0], wv[0], a);
        a = fmaf(xin[q*4+1], wv[1], a);
        a = fmaf(xin[q*4+2], wv[2], a);
        a = fmaf(xin[q*4+3], wv[3], a);
      }
      sv[j] = (short)f2b(fmaxf(a, 0.f));
    }
    *(short8*)&out[ob + cb*8] = sv;
  }
}

// ------- VQ via MFMA: z fp32 [131072,32] -> zq fp32 + loss partials ---------
__global__ __launch_bounds__(256) void vqm_k(const float* __restrict__ z,
    const float* __restrict__ embed, float* __restrict__ zq,
    float* __restrict__ partial) {
  __shared__ short Be[512*40];     // bf16 codes, pad stride 40 (40960 B)
  __shared__ float en[512];        // |e|^2 (bf16-rounded e), fp32
  __shared__ int   bidx[128];
  __shared__ float red[256];
  const int m0 = blockIdx.x * 128;
  for (int i = threadIdx.x; i < 4096; i += 256) {
    const int j = i >> 3, k0 = (i & 7) * 4;
    const f32x4 v = *(const f32x4*)&embed[j*32 + k0];
    s16x4 s;
    #pragma unroll
    for (int e = 0; e < 4; ++e) s[e] = (short)f2b(v[e]);
    *(s16x4*)&Be[j*40 + k0] = s;
  }
  __syncthreads();
  for (int j = threadIdx.x; j < 512; j += 256) {
    float s = 0.f;
    #pragma unroll
    for (int q = 0; q < 4; ++q) {
      const short8 v = *(const short8*)&Be[j*40 + q*8];
      #pragma unroll
      for (int e = 0; e < 8; ++e) {
        const float f = b2f((unsigned short)v[e]);
        s = fmaf(f, f, s);
      }
    }
    en[j] = s;
  }
  __syncthreads();
  const int w = threadIdx.x >> 6, l = threadIdx.x & 63;
  const int lm = l & 15, lk = l >> 4;
  const int rw = w * 32;
  short8 av[2];
  #pragma unroll
  for (int mi = 0; mi < 2; ++mi) {
    const float* zp = z + (long)(m0 + rw + mi*16 + lm)*32 + lk*8;
    const f32x4 f0 = *(const f32x4*)zp;
    const f32x4 f1 = *(const f32x4*)(zp + 4);
    short8 v;
    #pragma unroll
    for (int e = 0; e < 4; ++e) {
      v[e]     = (short)f2b(f0[e]);
      v[e + 4] = (short)f2b(f1[e]);
    }
    av[mi] = v;
  }
  float bd[2][4]; int bj[2][4];
  #pragma unroll
  for (int mi = 0; mi < 2; ++mi)
    #pragma unroll
    for (int r = 0; r < 4; ++r) { bd[mi][r] = 1e30f; bj[mi][r] = 0; }
  for (int nc = 0; nc < 8; ++nc) {               // N-chunks of 64 codes
    f32x4 acc[2][4];
    #pragma unroll
    for (int mi = 0; mi < 2; ++mi)
      #pragma unroll
      for (int ni = 0; ni < 4; ++ni) acc[mi][ni] = (f32x4)0.0f;
    #pragma unroll
    for (int ni = 0; ni < 4; ++ni) {
      const short8 bv = *(const short8*)&Be[(nc*64 + ni*16 + lm)*40 + lk*8];
      #pragma unroll
      for (int mi = 0; mi < 2; ++mi)
        acc[mi][ni] = __builtin_amdgcn_mfma_f32_16x16x32_bf16(
            __builtin_bit_cast(bf16x8, av[mi]),
            __builtin_bit_cast(bf16x8, bv),
            acc[mi][ni], 0, 0, 0);
    }
    #pragma unroll
    for (int ni = 0; ni < 4; ++ni) {
      const int j = nc*64 + ni*16 + lm;
      const float e_n = en[j];
      #pragma unroll
      for (int mi = 0; mi < 2; ++mi)
        #pragma unroll
        for (int r = 0; r < 4; ++r) {
          const float d = fmaf(-2.f, acc[mi][ni][r], e_n);
          if (d < bd[mi][r]) { bd[mi][r] = d; bj[mi][r] = j; }
        }
    }
  }
  #pragma unroll
  for (int mi = 0; mi < 2; ++mi)
    #pragma unroll
    for (int r = 0; r < 4; ++r) {
      float d = bd[mi][r]; int j = bj[mi][r];
      #pragma unroll
      for (int off = 1; off < 16; off <<= 1) {
        const float od = __shfl_xor(d, off);
        const int   oj = __shfl_xor(j, off);
        if (od < d || (od == d && oj < j)) { d = od; j = oj; }
      }
      if (lm == 0) bidx[rw + mi*16 + lk*4 + r] = j;
    }
  __syncthreads();
  const int pl = threadIdx.x >> 1, hf = (threadIdx.x & 1) * 16;
  const int code = bidx[pl];
  const long pb = (long)(m0 + pl)*32 + hf;
  float se = 0.f;
  #pragma unroll
  for (int q = 0; q < 4; ++q) {
    const f32x4 ev = *(const f32x4*)&embed[code*32 + hf + q*4];
    const f32x4 zv = *(const f32x4*)&z[pb + q*4];
    *(f32x4*)&zq[pb + q*4] = ev;
    const f32x4 df = ev - zv;
    #pragma unroll
    for (int e = 0; e < 4; ++e) se = fmaf(df[e], df[e], se);
  }
  red[threadIdx.x] = se; __syncthreads();
  for (int s = 128; s > 0; s >>= 1) {
    if (threadIdx.x < s) red[threadIdx.x] += red[threadIdx.x + s];
    __syncthreads();
  }
  if (threadIdx.x == 0) partial[blockIdx.x] = red[0];
}

__global__ __launch_bounds__(256) void loss_k(const float* __restrict__ part,
                                              float* __restrict__ out) {
  __shared__ float red[256];
  const int t = threadIdx.x;
  float s = 0.f;
  #pragma unroll
  for (int q = 0; q < 4; ++q) s += part[t + q*256];   // 1024 partials
  red[t] = s; __syncthreads();
  for (int st = 128; st > 0; st >>= 1) {
    if (t < st) red[t] += red[t + st];
    __syncthreads();
  }
  if (t == 0) out[0] = red[0] * (1.25f / (131072.f * 32.f));
}

// ---- convt3 via MFMA: d2 NHWC bf16 [32,128,128,64] -> x_recon NCHW fp32 ----
// Block = (n, input row q, x-half h); wave w = parity (py=w>>1, px=w&1).
// Per wave: M=64 output cols (4 m-tiles), N=16 (co, 3 used), K=256 (a,b,ci).
// IL staging identical to the proven conflict-free layout; B frags (8/wave)
// from prepped wq6, loaded once. Zero-padded halo rows give exact-0 taps.
__global__ __launch_bounds__(256) void convt3m_k(const unsigned short* __restrict__ in,
    const unsigned short* __restrict__ wq6, const float* __restrict__ bias,
    float* __restrict__ out) {
  __shared__ short8 IL[3*8*66];      // [(r*8+c8)*66 + ixl], 25344 B
  const int h = blockIdx.x & 1, q = (blockIdx.x >> 1) & 127, n = blockIdx.x >> 8;
  for (int i = threadIdx.x; i < 1584; i += 256) {   // 3*66*8
    const int c8 = i & 7, t = i >> 3, ixl = t % 66, r = t / 66;
    const int iy = q - 1 + r, ix = h*64 - 1 + ixl;
    short8 v = (short8)(short)0;
    if (iy >= 0 && iy < 128 && ix >= 0 && ix < 128)
      v = *(const short8*)(in + (((long)(n*128 + iy)*128 + ix)*64 + c8*8));
    IL[(r*8 + c8)*66 + ixl] = v;
  }
  const int w = threadIdx.x >> 6, l = threadIdx.x & 63;
  const int py = w >> 1, px = w & 1;
  const int lm = l & 15, lk = l >> 4;
  short8 bfrag[8];
  #pragma unroll
  for (int kc = 0; kc < 8; ++kc)
    bfrag[kc] = *(const short8*)(wq6 + (((w*8 + kc)*64 + l) << 3));
  __syncthreads();
  f32x4 acc[4];
  #pragma unroll
  for (int mi = 0; mi < 4; ++mi) acc[mi] = (f32x4)0.0f;
  #pragma unroll
  for (int kc = 0; kc < 8; ++kc) {
    const int a = kc >> 2, b = (kc >> 1) & 1, ch = kc & 1;
    const int base = (((py + a)*8 + ch*4 + lk)*66) + px + b;   // + ixl(xq)
    #pragma unroll
    for (int mi = 0; mi < 4; ++mi) {
      const short8 av = *(const short8*)&IL[base + mi*16 + lm];
      acc[mi] = __builtin_amdgcn_mfma_f32_16x16x32_bf16(
          __builtin_bit_cast(bf16x8, av),
          __builtin_bit_cast(bf16x8, bfrag[kc]),
          acc[mi], 0, 0, 0);
    }
  }
  // epilogue: C row = xq (lk*4+r within tile), col = co (lanes lm<3 write)
  if (lm < 3) {
    const float bv = bias[lm];
    const int oy = 2*q + py;
    const long ob = ((long)(n*3 + lm))*65536 + oy*256;
    #pragma unroll
    for (int mi = 0; mi < 4; ++mi)
      #pragma unroll
      for (int r = 0; r < 4; ++r) {
        const int xq = mi*16 + lk*4 + r;
        out[ob + h*128 + 2*xq + px] = acc[mi][r] + bv;
      }
  }
}

extern "C" void kernel_launch(void* const* d_in, const int* in_sizes, int n_in,
                              void* d_out, int out_size, void* d_ws, size_t ws_size,
                              hipStream_t stream) {
  const float* x   = (const float*)d_in[0];
  const float* ew1 = (const float*)d_in[1];  const float* eb1 = (const float*)d_in[2];
  const float* ew2 = (const float*)d_in[3];  const float* eb2 = (const float*)d_in[4];
  const float* ew3 = (const float*)d_in[5];  const float* eb3 = (const float*)d_in[6];
  const float* emb = (const float*)d_in[7];
  const float* dw1 = (const float*)d_in[8];  const float* db1 = (const float*)d_in[9];
  const float* dw2 = (const float*)d_in[10]; const float* db2 = (const float*)d_in[11];
  const float* dw3 = (const float*)d_in[12]; const float* db3 = (const float*)d_in[13];
  float* out = (float*)d_out;

  // ws layout (bytes), total 134,217,728:
  //   h1  NHWC bf16 [32,128,128,64]  @ 0          (67108864)   -> reused as d2
  //   h2  NHWC bf16 [32, 64, 64,128] @ 67108864   (33554432)   -> reused as d1
  //   z   f32  [131072,32]           @ 100663296  (16777216)
  //   zq  f32  [131072,32]           @ 117440512  (16777216)
  //   loss partials (1024 f32) @ 67108864 — h2 region, DEAD during vqm_k
  //     (R9 post-mortem: z is live inside vqm_k; h2 isn't).
  //   wq2/wq3 overlaid in zq region (dead until vqm writes zq);
  //   wq4/wq5/wq6 overlaid in z region (written after vqm, z dead then).
  uint8_t* w8 = (uint8_t*)d_ws;
  unsigned short* h1 = (unsigned short*)w8;
  unsigned short* h2 = (unsigned short*)(w8 + 67108864);
  float* z   = (float*)(w8 + 100663296);
  float* zq  = (float*)(w8 + 117440512);
  float* part = (float*)(w8 + 67108864);              // h2 region (dead @ vqm)
  unsigned short* wq2 = (unsigned short*)(w8 + 117440512);            // 262144 B
  unsigned short* wq3 = (unsigned short*)(w8 + 117440512 + 262144);   // 73728 B
  unsigned short* wq4 = (unsigned short*)(w8 + 100663296);            // 73728 B
  unsigned short* wq5 = (unsigned short*)(w8 + 100663296 + 73728);    // 262144 B
  unsigned short* wq6 = (unsigned short*)(w8 + 100663296 + 335872);   // 32768 B
  unsigned short* d1 = h2;
  unsigned short* d2 = h1;

  // encoder weight prep (into zq region, consumed before vqm writes zq)
  prep2_k<<<dim3(512),256,0,stream>>>(ew2, wq2);
  prep3_k<<<dim3(144),256,0,stream>>>(ew3, wq3);
  // encoder
  conv1_k<<<dim3(2048),256,0,stream>>>(x, ew1, eb1, h1);
  mconv_k<64,128,128,2,4,16,1,1,false,true,false,false>
      <<<dim3(1024),256,0,stream>>>(h1, wq2, eb2, h2);
  mconv_k<128,32,64,1,3,9,1,1,false,true,false,true>
      <<<dim3(1024),256,0,stream>>>(h2, wq3, eb3, z);
  // VQ (MFMA) + loss  (partials in h2 region; loss_k consumes before d1 write)
  vqm_k<<<dim3(1024),256,0,stream>>>(z, emb, zq, part);
  loss_k<<<dim3(1),256,0,stream>>>(part, out + 6291456);
  // decoder weight prep (into z region, dead after vqm)
  prep4_k<<<dim3(144),256,0,stream>>>(dw1, wq4);
  prep5_k<<<dim3(512),256,0,stream>>>(dw2, wq5);
  prep6_k<<<dim3(64),256,0,stream>>>(dw3, wq6);
  // decoder
  mconv_k<32,128,64,1,3,9,1,1,false,true,true,false>
      <<<dim3(1024),256,0,stream>>>(zq, wq4, db1, d1);
  mconv_k<128,64,64,1,2,4,2,0,true,true,false,false>
      <<<dim3(1024,4),256,0,stream>>>(d1, wq5, db2, d2);
  convt3m_k<<<dim3(8192),256,0,stream>>>(d2, wq6, db3, out);
}